// Round 15
// baseline (559.700 us; speedup 1.0000x reference)
//
#include <hip/hip_runtime.h>
#include <hip/hip_bf16.h>
#include <stdint.h>

#define T_DIM 16
#define B_DIM 4096
#define D_DIM 256
#define H_DIM 512
#define E_DIM 32
#define M_DIM (T_DIM * B_DIM)
#define BD_DIM (B_DIM * D_DIM)     // elems per term/pred slice
#define EPS_F 0.1f

#define NSLICE 16                  // H / SH
#define SH 32                      // h-columns per slice
#define HS_LD 40                   // Hs leading dim (pad 32->40: 16B-aligned, bank-spread)
#define MAXS 64

typedef __attribute__((ext_vector_type(8))) short short8;   // 8 bf16 (MFMA A/B frag)
typedef __attribute__((ext_vector_type(4))) float f32x4;    // MFMA C/D frag
typedef __attribute__((ext_vector_type(2))) float f32x2;    // 8B stream chunk

#define GLOBAL_AS __attribute__((address_space(1)))
#define LDS_AS __attribute__((address_space(3)))

__device__ __forceinline__ uint32_t f2bf_rne(float x) {
  uint32_t u = __float_as_uint(x);
  return (u + 0x7fffu + ((u >> 16) & 1u)) >> 16;
}

// ---- agg v6 (r13 configuration, RESTORED: nt hints back on all agg loads) ----
// r14 A/B proved nt helps (+50%): no-allocate keeps the once-read 256MB pred/inv
// stream from evicting useful L2/L3 lines. 78 us is the measured endpoint of the
// full lever matrix {structure, occupancy 19-77%, width 8-32B, nt on/off}.
// blockIdx.x >= 2048 -> weight-prep rider.
__global__ __launch_bounds__(256) void agg_prep_kernel(
    const float* __restrict__ term, const float* __restrict__ pred,
    const float* __restrict__ inv, const float* __restrict__ signs,
    const int* __restrict__ heads, const int* __restrict__ tails,
    const float* __restrict__ W1, const float* __restrict__ W2,
    uint16_t* __restrict__ agg, uint16_t* __restrict__ W1T, uint16_t* __restrict__ W2T) {
  const int tid = threadIdx.x;
  if (blockIdx.x >= 2048) {  // ---- prep path ----
    const int idx = (blockIdx.x - 2048) * 256 + tid;    // 0 .. 131071 == D*H
    const int d = idx >> 9, h = idx & (H_DIM - 1);
    W1T[h * D_DIM + d] = (uint16_t)f2bf_rne(W1[idx]);
    const int h2 = idx >> 8, d2 = idx & (D_DIM - 1);
    W2T[d2 * H_DIM + h2] = (uint16_t)f2bf_rne(W2[idx]);
    return;
  }

  __shared__ float Cm[T_DIM][T_DIM];      // agg[t] = sum_s Cm[t][s]*term[s] + streams
  __shared__ float Lsgn[T_DIM][MAXS];
  __shared__ uint64_t Lptr[T_DIM][MAXS];
  __shared__ int Lcnt[T_DIM];

  Cm[tid >> 4][tid & 15] = ((tid >> 4) == (tid & 15)) ? EPS_F : 0.f;
  if (tid < T_DIM) Lcnt[tid] = 0;
  __syncthreads();
  if (tid < E_DIM) {   // parallel build (round-8 verified)
    const int e = tid;
    const int hh = heads[e] & (T_DIM - 1);
    const int tt = tails[e] & (T_DIM - 1);
    const float s = signs[e];
    atomicAdd(&Cm[tt][hh], s);
    int i = atomicAdd(&Lcnt[tt], 1);
    Lsgn[tt][i] = s; Lptr[tt][i] = (uint64_t)(pred + (size_t)e * BD_DIM);
    atomicAdd(&Cm[hh][tt], s);
    i = atomicAdd(&Lcnt[hh], 1);
    Lsgn[hh][i] = s; Lptr[hh][i] = (uint64_t)(inv + (size_t)e * BD_DIM);
  }
  __syncthreads();

  const int j = (blockIdx.x * 256 + tid) * 2;   // 2-elem chunk in [0, B*D)

  f32x2 tr[T_DIM];
#pragma unroll
  for (int s = 0; s < T_DIM; ++s)
    tr[s] = __builtin_nontemporal_load(reinterpret_cast<const f32x2*>(term + (size_t)s * BD_DIM + j));

#pragma unroll 4
  for (int t = 0; t < T_DIM; ++t) {
    f32x4 cv[4];
#pragma unroll
    for (int q = 0; q < 4; ++q) cv[q] = *reinterpret_cast<const f32x4*>(&Cm[t][q * 4]);

    float a0 = 0.f, a1 = 0.f;
#pragma unroll
    for (int s = 0; s < T_DIM; ++s) {
      const float cs = cv[s >> 2][s & 3];
      a0 += cs * tr[s][0];
      a1 += cs * tr[s][1];
    }

    const int n = Lcnt[t];
#pragma unroll 4
    for (int i = 0; i < n; ++i) {
      const float sg = Lsgn[t][i];
      const float* bp = (const float*)Lptr[t][i];
      const f32x2 p = __builtin_nontemporal_load(reinterpret_cast<const f32x2*>(bp + j));
      a0 += sg * p[0];
      a1 += sg * p[1];
    }

    *reinterpret_cast<uint32_t*>(agg + (size_t)t * BD_DIM + j) =
        f2bf_rne(a0) | (f2bf_rne(a1) << 16);
  }
}

// ---- fused MLP v5: ZERO barriers -- wave-private rows, reg-resident W ----
// Each wave owns the SAME 16 rows in both GEMM phases, so its Hs slice (16x40 u16,
// 1.25 KB) is wave-private: no cross-wave hazard, no __syncthreads anywhere. Waves
// free-run across all 16 slices. W fragments live in registers, prefetched one phase
// ahead (w1f[s+1] between A(s) and B(s) hides under B's 16 MFMA; w2f[s+1] after B(s)
// hides under A(s+1)). This removes both v3's lockstep-latency problem and v4's 17
// barrier re-convergences. VGPR ~240 (af 32 + w1f 64 + w2f 64 + oacc 64); LDS 5 KB.
__global__ __launch_bounds__(256, 2) void mlp_fused(
    const uint16_t* __restrict__ A,     // agg, [M][256] bf16
    const uint16_t* __restrict__ W1T,   // [H=512][D=256] bf16
    const uint16_t* __restrict__ W2T,   // [D=256][H=512] bf16
    const float* __restrict__ b1, const float* __restrict__ b2,
    float* __restrict__ Out) {
  __shared__ __align__(16) uint16_t Hs[4][16 * HS_LD];   // per-wave private, 4x1.25 KB

  const int tid = threadIdx.x;
  const int w = tid >> 6;
  const int l = tid & 63;
  const int lane16 = l & 15;
  const int quad = l >> 4;
  const int m0 = blockIdx.x * 64;
  const int wrow = w * 16;            // this wave's 16 rows: m0+wrow .. m0+wrow+15
  uint16_t* hsw = Hs[w];              // wave-private Hs slice

  // ---- A fragments (16 rows x 256, loaded once from L3-resident agg) ----
  short8 af[8];
#pragma unroll
  for (int kk = 0; kk < 8; ++kk)
    af[kk] = *reinterpret_cast<const short8*>(
        A + (size_t)(m0 + wrow + lane16) * D_DIM + kk * 32 + quad * 8);

  // ---- prefetch W1/W2 fragments for slice 0 ----
  short8 w1f[2][8];   // [j: h-frag within slice][kk: k-step]
#pragma unroll
  for (int j = 0; j < 2; ++j)
#pragma unroll
    for (int kk = 0; kk < 8; ++kk)
      w1f[j][kk] = *reinterpret_cast<const short8*>(
          W1T + (size_t)(j * 16 + lane16) * D_DIM + kk * 32 + quad * 8);

  short8 w2f[16];     // [j: d-frag, all 256 out cols]
#pragma unroll
  for (int j = 0; j < 16; ++j)
    w2f[j] = *reinterpret_cast<const short8*>(
        W2T + (size_t)(j * 16 + lane16) * H_DIM + quad * 8);

  f32x4 oacc[16];
#pragma unroll
  for (int j = 0; j < 16; ++j) oacc[j] = (f32x4){0.f, 0.f, 0.f, 0.f};

#pragma unroll 1
  for (int s = 0; s < NSLICE; ++s) {
    // ===== phase A(s): hacc = af x w1f (16 MFMA); relu+bias -> private Hs =====
    f32x4 hacc[2];
#pragma unroll
    for (int j = 0; j < 2; ++j) hacc[j] = (f32x4){0.f, 0.f, 0.f, 0.f};
#pragma unroll
    for (int kk = 0; kk < 8; ++kk)
#pragma unroll
      for (int j = 0; j < 2; ++j)
        hacc[j] = __builtin_amdgcn_mfma_f32_16x16x32_bf16(af[kk], w1f[j][kk], hacc[j], 0, 0, 0);

#pragma unroll
    for (int j = 0; j < 2; ++j) {
      const int hloc = j * 16 + lane16;
      const float bv = b1[s * SH + hloc];
#pragma unroll
      for (int r = 0; r < 4; ++r) {
        const int row = quad * 4 + r;            // local row 0..15
        const float x = fmaxf(hacc[j][r] + bv, 0.f);
        hsw[row * HS_LD + hloc] = (uint16_t)f2bf_rne(x);
      }
    }

    // prefetch w1f for slice s+1 (regs free after phase A; latency hides under phase B)
    if (s < NSLICE - 1) {
#pragma unroll
      for (int j = 0; j < 2; ++j)
#pragma unroll
        for (int kk = 0; kk < 8; ++kk)
          w1f[j][kk] = *reinterpret_cast<const short8*>(
              W1T + (size_t)((s + 1) * SH + j * 16 + lane16) * D_DIM + kk * 32 + quad * 8);
    }

    // ===== phase B(s): oacc += Hs x w2f (16 MFMA; K=32 in one step) =====
    // af2: A-frag row=lane16 (local), k-elems h=quad*8..+7 (compiler inserts the
    // ds_write->ds_read lgkmcnt wait; same-wave dependency, no barrier needed)
    const short8 af2 = *reinterpret_cast<const short8*>(hsw + lane16 * HS_LD + quad * 8);
#pragma unroll
    for (int j = 0; j < 16; ++j)
      oacc[j] = __builtin_amdgcn_mfma_f32_16x16x32_bf16(af2, w2f[j], oacc[j], 0, 0, 0);

    // prefetch w2f for slice s+1 (hides under phase A(s+1))
    if (s < NSLICE - 1) {
#pragma unroll
      for (int j = 0; j < 16; ++j)
        w2f[j] = *reinterpret_cast<const short8*>(
            W2T + (size_t)(j * 16 + lane16) * H_DIM + (s + 1) * SH + quad * 8);
    }
  }

  // ---- epilogue: out = oacc + b2 ----
#pragma unroll
  for (int j = 0; j < 16; ++j) {
    const int col = j * 16 + lane16;
    const float bv = b2[col];
#pragma unroll
    for (int r = 0; r < 4; ++r) {
      const int row = m0 + wrow + quad * 4 + r;
      Out[(size_t)row * D_DIM + col] = oacc[j][r] + bv;
    }
  }
}

extern "C" void kernel_launch(void* const* d_in, const int* in_sizes, int n_in,
                              void* d_out, int out_size, void* d_ws, size_t ws_size,
                              hipStream_t stream) {
  const float* term  = (const float*)d_in[0];
  const float* pred  = (const float*)d_in[1];
  const float* inv   = (const float*)d_in[2];
  const float* signs = (const float*)d_in[3];
  const float* W1    = (const float*)d_in[4];
  const float* b1    = (const float*)d_in[5];
  const float* W2    = (const float*)d_in[6];
  const float* b2    = (const float*)d_in[7];
  const int* heads   = (const int*)d_in[8];
  const int* tails   = (const int*)d_in[9];

  char* ws = (char*)d_ws;
  uint16_t* W1T = (uint16_t*)(ws);              // 256 KB
  uint16_t* W2T = (uint16_t*)(ws + 262144);     // 256 KB
  uint16_t* agg = (uint16_t*)(ws + 524288);     // 32 MB

  // dispatch 1: agg v6 (blocks 0..2047, nt restored) + prep (blocks 2048..2559)
  agg_prep_kernel<<<dim3(2560), dim3(256), 0, stream>>>(
      term, pred, inv, signs, heads, tails, W1, W2, agg, W1T, W2T);
  // dispatch 2: fused MLP v5 (zero barriers, wave-private Hs, reg-resident W)
  mlp_fused<<<dim3(M_DIM / 64), dim3(256), 0, stream>>>(
      agg, W1T, W2T, b1, b2, (float*)d_out);
}

// Round 16
// 384.107 us; speedup vs baseline: 1.4571x; 1.4571x over previous
//
#include <hip/hip_runtime.h>
#include <hip/hip_bf16.h>
#include <stdint.h>

#define T_DIM 16
#define B_DIM 4096
#define D_DIM 256
#define H_DIM 512
#define E_DIM 32
#define M_DIM (T_DIM * B_DIM)
#define BD_DIM (B_DIM * D_DIM)     // elems per term/pred slice
#define EPS_F 0.1f

#define NSLICE 16                  // H / SH
#define SH 32                      // h-columns per slice
#define HS_LD 40                   // Hs leading dim (pad 32->40: 16B-aligned, bank-spread)
#define MAXS 64

typedef __attribute__((ext_vector_type(8))) short short8;   // 8 bf16 (MFMA A/B frag)
typedef __attribute__((ext_vector_type(4))) float f32x4;    // MFMA C/D frag

#define GLOBAL_AS __attribute__((address_space(1)))
#define LDS_AS __attribute__((address_space(3)))

__device__ __forceinline__ uint32_t f2bf_rne(float x) {
  uint32_t u = __float_as_uint(x);
  return (u + 0x7fffu + ((u >> 16) & 1u)) >> 16;
}

// ---- agg v5 (r12 configuration, best-measured: 4-elem chunks, nt loads) ----
// Matrix completed over the session: {branchy/list/reg-term structures, occupancy
// 19-77%, access width 8-32B, nt on/off}. Floor: ~78 us = 352 MB compulsory traffic
// at ~4.5 TB/s vector-path on a 9-stream gather mix. nt is REQUIRED (r14 A/B: removing
// it costs +50% -- no-allocate keeps the once-read 256MB pred/inv stream from evicting
// useful L2/L3 lines). blockIdx.x >= 1024 -> weight-prep rider.
__global__ __launch_bounds__(256) void agg_prep_kernel(
    const float* __restrict__ term, const float* __restrict__ pred,
    const float* __restrict__ inv, const float* __restrict__ signs,
    const int* __restrict__ heads, const int* __restrict__ tails,
    const float* __restrict__ W1, const float* __restrict__ W2,
    uint16_t* __restrict__ agg, uint16_t* __restrict__ W1T, uint16_t* __restrict__ W2T) {
  const int tid = threadIdx.x;
  if (blockIdx.x >= 1024) {  // ---- prep path ----
    const int idx = (blockIdx.x - 1024) * 256 + tid;    // 0 .. 131071 == D*H
    const int d = idx >> 9, h = idx & (H_DIM - 1);
    W1T[h * D_DIM + d] = (uint16_t)f2bf_rne(W1[idx]);
    const int h2 = idx >> 8, d2 = idx & (D_DIM - 1);
    W2T[d2 * H_DIM + h2] = (uint16_t)f2bf_rne(W2[idx]);
    return;
  }

  __shared__ float Cm[T_DIM][T_DIM];      // agg[t] = sum_s Cm[t][s]*term[s] + streams
  __shared__ float Lsgn[T_DIM][MAXS];
  __shared__ uint64_t Lptr[T_DIM][MAXS];
  __shared__ int Lcnt[T_DIM];

  Cm[tid >> 4][tid & 15] = ((tid >> 4) == (tid & 15)) ? EPS_F : 0.f;
  if (tid < T_DIM) Lcnt[tid] = 0;
  __syncthreads();
  if (tid < E_DIM) {   // parallel build (round-8 verified)
    const int e = tid;
    const int hh = heads[e] & (T_DIM - 1);
    const int tt = tails[e] & (T_DIM - 1);
    const float s = signs[e];
    atomicAdd(&Cm[tt][hh], s);
    int i = atomicAdd(&Lcnt[tt], 1);
    Lsgn[tt][i] = s; Lptr[tt][i] = (uint64_t)(pred + (size_t)e * BD_DIM);
    atomicAdd(&Cm[hh][tt], s);
    i = atomicAdd(&Lcnt[hh], 1);
    Lsgn[hh][i] = s; Lptr[hh][i] = (uint64_t)(inv + (size_t)e * BD_DIM);
  }
  __syncthreads();

  const int j = (blockIdx.x * 256 + tid) * 4;   // 4-elem chunk in [0, B*D)

  f32x4 tr[T_DIM];
#pragma unroll
  for (int s = 0; s < T_DIM; ++s)
    tr[s] = __builtin_nontemporal_load(reinterpret_cast<const f32x4*>(term + (size_t)s * BD_DIM + j));

#pragma unroll 2
  for (int t = 0; t < T_DIM; ++t) {
    f32x4 cv[4];
#pragma unroll
    for (int q = 0; q < 4; ++q) cv[q] = *reinterpret_cast<const f32x4*>(&Cm[t][q * 4]);

    float acc[4] = {0.f, 0.f, 0.f, 0.f};
#pragma unroll
    for (int s = 0; s < T_DIM; ++s) {
      const float cs = cv[s >> 2][s & 3];
#pragma unroll
      for (int k = 0; k < 4; ++k) acc[k] += cs * tr[s][k];
    }

    const int n = Lcnt[t];
#pragma unroll 2
    for (int i = 0; i < n; ++i) {
      const float sg = Lsgn[t][i];
      const float* bp = (const float*)Lptr[t][i];
      const f32x4 p = __builtin_nontemporal_load(reinterpret_cast<const f32x4*>(bp + j));
#pragma unroll
      for (int k = 0; k < 4; ++k) acc[k] += sg * p[k];
    }

    uint2 pk;
    pk.x = f2bf_rne(acc[0]) | (f2bf_rne(acc[1]) << 16);
    pk.y = f2bf_rne(acc[2]) | (f2bf_rne(acc[3]) << 16);
    *reinterpret_cast<uint2*>(agg + (size_t)t * BD_DIM + j) = pk;
  }
}

// ---- fused MLP v4 (r12, best-measured) + nt Out stores (single change this round) ----
// A in registers; W coop-staged via global_load_lds; Wb1/Wb2/Hs double-buffered;
// ONE barrier per slice. r15 lesson: launch_bounds(256,2) caps VGPR at 128 -- v4's
// ~84 VGPR fits; reg-resident-W designs (v3/v5) cannot. Out is a 64MB write-once
// stream -> nontemporal store (r14 proved allocation policy is first-order here).
__global__ __launch_bounds__(256, 2) void mlp_fused(
    const uint16_t* __restrict__ A,     // agg, [M][256] bf16
    const uint16_t* __restrict__ W1T,   // [H=512][D=256] bf16
    const uint16_t* __restrict__ W2T,   // [D=256][H=512] bf16
    const float* __restrict__ b1, const float* __restrict__ b2,
    float* __restrict__ Out) {
  __shared__ __align__(16) uint16_t Wb1[2][SH * 256];   // [kc=0..7][hl=0..31][32]
  __shared__ __align__(16) uint16_t Wb2[2][SH * 256];   // [d=0..255][32]
  __shared__ __align__(16) uint16_t Hs[2][64 * HS_LD];

  const int tid = threadIdx.x;
  const int w = tid >> 6;
  const int l = tid & 63;
  const int lane16 = l & 15;
  const int quad = l >> 4;
  const int m0 = blockIdx.x * 64;

  const int wm  = (w & 1) * 32;
  const int wnA = ((w >> 1) & 1) * 16;
  const int wn2 = ((w >> 1) & 1) * 128;

#define STAGE_W1(sl, buf)                                                           \
  {                                                                                 \
    _Pragma("unroll")                                                               \
    for (int p = 0; p < 4; ++p) {                                                   \
      const int off = p * 2048 + tid * 8; /* == kc*1024 + hl*32 + c */              \
      const int kc = off >> 10;                                                     \
      const int hl = (off >> 5) & 31;                                               \
      const int c = off & 31;                                                       \
      const uint16_t* g = W1T + (size_t)((sl) * SH + hl) * D_DIM + kc * 32 + c;     \
      __builtin_amdgcn_global_load_lds((const GLOBAL_AS uint32_t*)g,                \
                                       (LDS_AS uint32_t*)(Wb1[buf] + off), 16, 0, 0); \
    }                                                                               \
  }
#define STAGE_W2(sl, buf)                                                           \
  {                                                                                 \
    _Pragma("unroll")                                                               \
    for (int p = 0; p < 4; ++p) {                                                   \
      const int off = p * 2048 + tid * 8; /* == d*32 + c */                         \
      const int d = off >> 5;                                                       \
      const int c = off & 31;                                                       \
      const uint16_t* g = W2T + (size_t)d * H_DIM + (sl) * SH + c;                  \
      __builtin_amdgcn_global_load_lds((const GLOBAL_AS uint32_t*)g,                \
                                       (LDS_AS uint32_t*)(Wb2[buf] + off), 16, 0, 0); \
    }                                                                               \
  }

  // ---- prologue stages: W1[0]->Wb1[0], W1[1]->Wb1[1], W2[0]->Wb2[0] ----
  STAGE_W1(0, 0);
  STAGE_W1(1, 1);
  STAGE_W2(0, 0);

  // ---- A-tile -> registers ----
  short8 af[2][8];
#pragma unroll
  for (int i = 0; i < 2; ++i)
#pragma unroll
    for (int kk = 0; kk < 8; ++kk)
      af[i][kk] = *reinterpret_cast<const short8*>(
          A + (size_t)(m0 + wm + i * 16 + lane16) * D_DIM + kk * 32 + quad * 8);

  f32x4 oacc[2][8];
#pragma unroll
  for (int i = 0; i < 2; ++i)
#pragma unroll
    for (int j = 0; j < 8; ++j) oacc[i][j] = (f32x4){0.f, 0.f, 0.f, 0.f};

  __syncthreads();   // prologue stages drained; af resident

#define PHASE_A(sl)                                                                 \
  {                                                                                 \
    f32x4 hacc[2];                                                                  \
    _Pragma("unroll")                                                               \
    for (int i = 0; i < 2; ++i) hacc[i] = (f32x4){0.f, 0.f, 0.f, 0.f};              \
    const uint16_t* wb = Wb1[(sl) & 1];                                             \
    _Pragma("unroll")                                                               \
    for (int kk = 0; kk < 8; ++kk) {                                                \
      const short8 bfr = *reinterpret_cast<const short8*>(                          \
          wb + kk * 1024 + (wnA + lane16) * 32 + quad * 8);                         \
      _Pragma("unroll")                                                             \
      for (int i = 0; i < 2; ++i)                                                   \
        hacc[i] = __builtin_amdgcn_mfma_f32_16x16x32_bf16(af[i][kk], bfr, hacc[i], 0, 0, 0); \
    }                                                                               \
    const int hloc = wnA + lane16;                                                  \
    const float bv = b1[(sl) * SH + hloc];                                          \
    uint16_t* hsb = Hs[(sl) & 1];                                                   \
    _Pragma("unroll")                                                               \
    for (int i = 0; i < 2; ++i) {                                                   \
      _Pragma("unroll")                                                             \
      for (int r = 0; r < 4; ++r) {                                                 \
        const int row = wm + i * 16 + quad * 4 + r;                                 \
        const float x = fmaxf(hacc[i][r] + bv, 0.f);                                \
        hsb[row * HS_LD + hloc] = (uint16_t)f2bf_rne(x);                            \
      }                                                                             \
    }                                                                               \
  }

  PHASE_A(0);

  for (int s = 0; s < NSLICE; ++s) {
    __syncthreads();   // Hs[s&1] + Wb2[s&1] (+ Wb1[(s+1)&1]) all resident

    if (s + 2 <= NSLICE - 1) STAGE_W1(s + 2, s & 1);
    if (s + 1 <= NSLICE - 1) STAGE_W2(s + 1, (s + 1) & 1);

    // ===== phase B(s): oacc += Hs[s&1] x Wb2[s&1] =====
    {
      const uint16_t* hsb = Hs[s & 1];
      const uint16_t* wb = Wb2[s & 1];
      short8 af2[2], w2f[8];
#pragma unroll
      for (int i = 0; i < 2; ++i)
        af2[i] = *reinterpret_cast<const short8*>(hsb + (wm + i * 16 + lane16) * HS_LD + quad * 8);
#pragma unroll
      for (int j = 0; j < 8; ++j)
        w2f[j] = *reinterpret_cast<const short8*>(wb + (wn2 + j * 16 + lane16) * 32 + quad * 8);
#pragma unroll
      for (int i = 0; i < 2; ++i)
#pragma unroll
        for (int j = 0; j < 8; ++j)
          oacc[i][j] = __builtin_amdgcn_mfma_f32_16x16x32_bf16(af2[i], w2f[j], oacc[i][j], 0, 0, 0);
    }

    if (s + 1 <= NSLICE - 1) PHASE_A(s + 1);
  }

  // ---- final epilogue: nontemporal stores (write-once stream, don't pollute L2/L3) ----
#pragma unroll
  for (int j = 0; j < 8; ++j) {
    const int col = wn2 + j * 16 + lane16;
    const float bv = b2[col];
#pragma unroll
    for (int i = 0; i < 2; ++i) {
#pragma unroll
      for (int r = 0; r < 4; ++r) {
        const int row = m0 + wm + i * 16 + quad * 4 + r;
        __builtin_nontemporal_store(oacc[i][j][r] + bv, Out + (size_t)row * D_DIM + col);
      }
    }
  }
#undef STAGE_W1
#undef STAGE_W2
#undef PHASE_A
}

extern "C" void kernel_launch(void* const* d_in, const int* in_sizes, int n_in,
                              void* d_out, int out_size, void* d_ws, size_t ws_size,
                              hipStream_t stream) {
  const float* term  = (const float*)d_in[0];
  const float* pred  = (const float*)d_in[1];
  const float* inv   = (const float*)d_in[2];
  const float* signs = (const float*)d_in[3];
  const float* W1    = (const float*)d_in[4];
  const float* b1    = (const float*)d_in[5];
  const float* W2    = (const float*)d_in[6];
  const float* b2    = (const float*)d_in[7];
  const int* heads   = (const int*)d_in[8];
  const int* tails   = (const int*)d_in[9];

  char* ws = (char*)d_ws;
  uint16_t* W1T = (uint16_t*)(ws);              // 256 KB
  uint16_t* W2T = (uint16_t*)(ws + 262144);     // 256 KB
  uint16_t* agg = (uint16_t*)(ws + 524288);     // 32 MB

  // dispatch 1: agg v5 (blocks 0..1023, 4-elem chunks, nt) + prep (blocks 1024..1535)
  agg_prep_kernel<<<dim3(1536), dim3(256), 0, stream>>>(
      term, pred, inv, signs, heads, tails, W1, W2, agg, W1T, W2T);
  // dispatch 2: fused MLP v4 + nt Out (A in regs, 1 barrier/slice, full dbuf)
  mlp_fused<<<dim3(M_DIM / 64), dim3(256), 0, stream>>>(
      agg, W1T, W2T, b1, b2, (float*)d_out);
}